// Round 23
// baseline (440.853 us; speedup 1.0000x reference)
//
#include <hip/hip_runtime.h>
#include <math.h>

#define T_LEN 3000
#define NF 97
#define NB 64
#define NH 256
#define NI 100
#define SEQ 6336       // Pt row width: 64 x-cols + 6208 filter cols
#define KCO 16         // k_out K-chunk (16 chunks of 16)
#define KS 10          // k_ugemm split-K factor
#define KPB 300        // k per split = 3000/KS
#define KC2 15         // k_ugemm K-chunk (20 chunks of 15)
#define UPROWS 6400
#define LF 101         // segment length (30*101 = 3030 ext samples)
#define NSEG 30
#define WTS 3072       // W1T row stride (t padded to 3072)
#define VTS 6400       // Vt row stride

__device__ __forceinline__ void gload16(const float* g, float* l) {
    __builtin_amdgcn_global_load_lds(
        (const __attribute__((address_space(1))) void*)g,
        (__attribute__((address_space(3))) void*)l, 16, 0, 0);
}

// ---------------- k_init: merged prep (x^T) + W1 transpose + hom table ----
// blocks 0..46: Pt cols 0..63; 47..238: W1T; 239..245: H/Mfd.
__global__ __launch_bounds__(256) void k_init(
    const float* __restrict__ x, const float* __restrict__ W1,
    const float* __restrict__ a_all, float* __restrict__ Pt,
    float* __restrict__ W1T, double* __restrict__ H, double* __restrict__ Mfd)
{
    const int blk = blockIdx.x;
    if (blk < 47) {                       // ---- prep
        const int kk0 = blk * 64;
        const int b   = threadIdx.x & 63;
        const int ko  = threadIdx.x >> 6;
        #pragma unroll
        for (int p = 0; p < 16; ++p) {
            int kk = kk0 + ko + 4*p;
            if (kk < T_LEN) Pt[(size_t)kk*SEQ + b] = x[(size_t)b*T_LEN + kk];
        }
    } else if (blk < 239) {               // ---- W1 -> W1T (48 x 4 tiles)
        __shared__ float tile[64][65];
        const int w  = blk - 47;
        const int tb = w % 48;
        const int hb = w / 48;
        const int lt = threadIdx.x & 63, lw = threadIdx.x >> 6;
        #pragma unroll
        for (int i = 0; i < 16; ++i) {
            int t = tb*64 + lw*16 + i; if (t > T_LEN-1) t = T_LEN-1;
            tile[lw*16+i][lt] = W1[(size_t)t*NH + hb*64 + lt];
        }
        __syncthreads();
        #pragma unroll
        for (int i = 0; i < 16; ++i) {
            int h = hb*64 + lw*16 + i;
            W1T[(size_t)h*WTS + tb*64 + lt] = tile[lt][lw*16+i];
        }
    } else {                              // ---- hom: H[f][j][i], M^101
        if (threadIdx.x >= 64) return;
        const int ft = (blk - 239)*64 + threadIdx.x;
        const int f = ft >> 2, ib = ft & 3;
        if (f >= NF) return;
        const double a1 = a_all[f*5+1], a2 = a_all[f*5+2],
                     a3 = a_all[f*5+3], a4 = a_all[f*5+4];
        double z0 = (ib==0), z1 = (ib==1), z2 = (ib==2), z3 = (ib==3);
        for (int j = 0; j <= LF; ++j) {
            if (j < LF) H[((size_t)f*LF + j)*4 + ib] = z0;
            if (j == LF) {
                Mfd[f*16 + 0*4 + ib] = z0; Mfd[f*16 + 1*4 + ib] = z1;
                Mfd[f*16 + 2*4 + ib] = z2; Mfd[f*16 + 3*4 + ib] = z3;
                break;
            }
            double yv = z0;
            z0 = z1 - a1*yv; z1 = z2 - a2*yv; z2 = z3 - a3*yv; z3 = -a4*yv;
        }
    }
}

#define COEFS \
    const double bc0 = b_all[f*5+0], bc1 = b_all[f*5+1], bc2 = b_all[f*5+2], \
                 bc3 = b_all[f*5+3], bc4 = b_all[f*5+4]; \
    const double ac1 = a_all[f*5+1], ac2 = a_all[f*5+2], \
                 ac3 = a_all[f*5+3], ac4 = a_all[f*5+4];

#define FSTEP(XV, DST) { double xv = (XV); \
    double yv = fma(bc0, xv, z0); \
    z0 = fma(bc1, xv, z1) - ac1*yv; \
    z1 = fma(bc2, xv, z2) - ac2*yv; \
    z2 = fma(bc3, xv, z3) - ac3*yv; \
    z3 = bc4*xv - ac4*yv; \
    DST = (float)yv; }

// ---------------- k_seg_fwd: zero-state forward pass per segment ----------
// Segment p covers ext [101p, 101p+101). p==0: 15 edge + kk 0..85;
// p 1..28: kk 101p-15 .. 101p+85; p==29: kk 2914..2999 + 15 YRb.
__global__ __launch_bounds__(64) void k_seg_fwd(
    float* Pt, const float* __restrict__ b_all, const float* __restrict__ a_all,
    const float* __restrict__ zi_all, float* __restrict__ YRb,
    double* __restrict__ Zef)
{
    const int f = blockIdx.x, p = blockIdx.y, b = threadIdx.x;
    COEFS
    const float* xc = Pt + b;
    float* ycol = Pt + 64 + (size_t)f*64 + b;
    double z0 = 0, z1 = 0, z2 = 0, z3 = 0;

    if (p == 0) {
        const double x0 = (double)xc[0];
        const double e0 = 2.0*x0 - (double)xc[(size_t)15*SEQ];
        z0 = (double)zi_all[f*4+0]*e0; z1 = (double)zi_all[f*4+1]*e0;
        z2 = (double)zi_all[f*4+2]*e0; z3 = (double)zi_all[f*4+3]*e0;
        float le[15];
        #pragma unroll
        for (int i = 0; i < 15; ++i) le[i] = xc[(size_t)(15-i)*SEQ];
        #pragma unroll
        for (int i = 0; i < 15; ++i) { float o; FSTEP(2.0*x0 - (double)le[i], o); (void)o; }
    }
    int kk0, n;
    if (p == 0)            { kk0 = 0;          n = 86;  }
    else if (p < NSEG-1)   { kk0 = p*LF - 15;  n = LF;  }
    else                   { kk0 = 2914;       n = 86;  }

    {
        const int nc = n/20, rem = n - nc*20;
        float A[20], B[20], C[20];
#define LDF(BUF, c) { _Pragma("unroll") \
        for (int j = 0; j < 20; ++j) BUF[j] = xc[(size_t)(kk0+(c)*20+j)*SEQ]; }
#define CHF(BUF, c) { _Pragma("unroll") \
        for (int j = 0; j < 20; ++j) { float o; FSTEP((double)BUF[j], o); \
            ycol[(size_t)(kk0+(c)*20+j)*SEQ] = o; } }
        if (nc > 0) LDF(A, 0); if (nc > 1) LDF(B, 1); if (nc > 2) LDF(C, 2);
        for (int g = 0; g < nc; g += 3) {
            CHF(A, g); if (g+3 < nc) LDF(A, g+3);
            if (g+1 < nc) { CHF(B, g+1); if (g+4 < nc) LDF(B, g+4); }
            if (g+2 < nc) { CHF(C, g+2); if (g+5 < nc) LDF(C, g+5); }
        }
        if (rem) {
            float T[19];
            #pragma unroll
            for (int j = 0; j < 19; ++j) if (j < rem) T[j] = xc[(size_t)(kk0+nc*20+j)*SEQ];
            #pragma unroll
            for (int j = 0; j < 19; ++j) if (j < rem) {
                float o; FSTEP((double)T[j], o); ycol[(size_t)(kk0+nc*20+j)*SEQ] = o;
            }
        }
#undef LDF
#undef CHF
    }
    if (p == NSEG-1) {
        const double xl = (double)xc[(size_t)(T_LEN-1)*SEQ];
        float re[15];
        #pragma unroll
        for (int i = 0; i < 15; ++i) re[i] = xc[(size_t)(2998-i)*SEQ];
        #pragma unroll
        for (int i = 0; i < 15; ++i) {
            float o; FSTEP(2.0*xl - (double)re[i], o);
            YRb[((size_t)f*15 + i)*64 + b] = o;
        }
    }
    double* ze = Zef + (((size_t)f*NSEG + p)*64 + b)*4;
    ze[0] = z0; ze[1] = z1; ze[2] = z2; ze[3] = z3;
}

// ---------------- k_stitch: boundary-state recurrence (M = M^101) ---------
__global__ __launch_bounds__(64) void k_stitch(
    const double* __restrict__ Ze, const double* __restrict__ Mm,
    double* __restrict__ Zo)
{
    const int f = blockIdx.x, b = threadIdx.x;
    double m[16];
    #pragma unroll
    for (int r = 0; r < 16; ++r) m[r] = Mm[f*16 + r];
    const double* z0p = Ze + (((size_t)f*NSEG + 0)*64 + b)*4;
    double z0 = z0p[0], z1 = z0p[1], z2 = z0p[2], z3 = z0p[3];
    {   double* o = Zo + (((size_t)f*NSEG + 1)*64 + b)*4;
        o[0]=z0; o[1]=z1; o[2]=z2; o[3]=z3; }
    for (int p = 1; p <= NSEG-2; ++p) {
        const double* zep = Ze + (((size_t)f*NSEG + p)*64 + b)*4;
        double n0 = zep[0] + m[0]*z0  + m[1]*z1  + m[2]*z2  + m[3]*z3;
        double n1 = zep[1] + m[4]*z0  + m[5]*z1  + m[6]*z2  + m[7]*z3;
        double n2 = zep[2] + m[8]*z0  + m[9]*z1  + m[10]*z2 + m[11]*z3;
        double n3 = zep[3] + m[12]*z0 + m[13]*z1 + m[14]*z2 + m[15]*z3;
        z0 = n0; z1 = n1; z2 = n2; z3 = n3;
        double* o = Zo + (((size_t)f*NSEG + p + 1)*64 + b)*4;
        o[0]=z0; o[1]=z1; o[2]=z2; o[3]=z3;
    }
}

// ---------------- k_seg_bwd: 101-aligned bwd segments, fwd-corr fused -----
// Block bq covers ext [101q, 101q+101), q = 29-bq; fwd-corr state zfd[q]
// constant per block (w=0 for q==0). Corrected read:
// float(double(y_raw) + H[j]*w), j = kk + 15 - 101q => bit-identical chain.
__global__ __launch_bounds__(64) void k_seg_bwd(
    float* Pt, const float* __restrict__ b_all, const float* __restrict__ a_all,
    const float* __restrict__ zi_all, const float* __restrict__ YRb,
    const double* __restrict__ H, const double* __restrict__ Zf,
    double* __restrict__ Zeb)
{
    const int f = blockIdx.x, bq = blockIdx.y, b = threadIdx.x;
    COEFS
    const int q = (NSEG-1) - bq;
    float* ycol = Pt + 64 + (size_t)f*64 + b;
    const float* yrp = YRb + (size_t)f*15*64 + b;
    const double* Hf = H + (size_t)f*LF*4;
    double w0 = 0, w1 = 0, w2 = 0, w3 = 0;
    if (q >= 1) {
        const double* zp = Zf + (((size_t)f*NSEG + q)*64 + b)*4;
        w0 = zp[0]; w1 = zp[1]; w2 = zp[2]; w3 = zp[3];
    }
    double z0 = 0, z1 = 0, z2 = 0, z3 = 0;

#define CORR(J) (Hf[(J)*4+0]*w0 + Hf[(J)*4+1]*w1 + Hf[(J)*4+2]*w2 + Hf[(J)*4+3]*w3)

    if (bq == 0) {
        // corrected yl at ext 3029 (j = 100 within fwd seg 29)
        const float ylf = (float)((double)yrp[14*64] + CORR(100));
        const double yl = (double)ylf;
        z0 = (double)zi_all[f*4+0]*yl; z1 = (double)zi_all[f*4+1]*yl;
        z2 = (double)zi_all[f*4+2]*yl; z3 = (double)zi_all[f*4+3]*yl;
        // 15 edge steps: ext 3029-i, j = 100-i (corrected YRb, outputs discarded)
        float t15[15];
        #pragma unroll
        for (int i = 0; i < 15; ++i)
            t15[i] = (float)((double)yrp[(size_t)(14-i)*64] + CORR(100-i));
        #pragma unroll
        for (int i = 0; i < 15; ++i) { float o; FSTEP((double)t15[i], o); (void)o; }
    }
    // stored range: bq==0: kk 2999..2914 (86); bq 1..28: kk 101q+85..101q-15
    // (101); bq==29: kk 85..0 (86). j = kk + 15 - 101*q (w=0 when q==0).
    const int kkH  = (bq == 0) ? 2999 : LF*q + 85;
    const int n    = (bq == 0 || bq == NSEG-1) ? 86 : LF;
    const int joff = 15 - LF*q;

    {
        const int nc = n/20, rem = n - nc*20;
        float A[20], B[20], C[20];
#define LDBc(BUF, c) { _Pragma("unroll") \
        for (int j = 0; j < 20; ++j) { \
            const int kk = kkH-19-20*(c)+j; \
            BUF[j] = (float)((double)ycol[(size_t)kk*SEQ] + CORR(kk + joff)); } }
#define CHBc(BUF, c) { _Pragma("unroll") \
        for (int j = 19; j >= 0; --j) { float o; FSTEP((double)BUF[j], o); BUF[j] = o; } \
        _Pragma("unroll") \
        for (int j = 0; j < 20; ++j) ycol[(size_t)(kkH-19-20*(c)+j)*SEQ] = BUF[j]; }
        if (nc > 0) LDBc(A, 0); if (nc > 1) LDBc(B, 1); if (nc > 2) LDBc(C, 2);
        for (int g = 0; g < nc; g += 3) {
            CHBc(A, g); if (g+3 < nc) LDBc(A, g+3);
            if (g+1 < nc) { CHBc(B, g+1); if (g+4 < nc) LDBc(B, g+4); }
            if (g+2 < nc) { CHBc(C, g+2); if (g+5 < nc) LDBc(C, g+5); }
        }
        if (rem) {
            float T[19];
            #pragma unroll
            for (int j = 0; j < 19; ++j) if (j < rem) {
                const int kk = kkH - 20*nc - j;
                T[j] = (float)((double)ycol[(size_t)kk*SEQ] + CORR(kk + joff));
            }
            #pragma unroll
            for (int j = 0; j < 19; ++j) if (j < rem) {
                float o; FSTEP((double)T[j], o); ycol[(size_t)(kkH-20*nc-j)*SEQ] = o;
            }
        }
#undef LDBc
#undef CHBc
    }
#undef CORR
    double* ze = Zeb + (((size_t)f*NSEG + bq)*64 + b)*4;
    ze[0] = z0; ze[1] = z1; ze[2] = z2; ze[3] = z3;
}

// ---------------- k_corr_bwd: aligned blocks bq = 1..29 -------------------
__global__ __launch_bounds__(64) void k_corr_bwd(
    float* Pt, const double* __restrict__ H, const double* __restrict__ Zb)
{
    const int f = blockIdx.x, bq = blockIdx.y + 1, b = threadIdx.x;
    const int q = (NSEG-1) - bq;
    const double* zp = Zb + (((size_t)f*NSEG + bq)*64 + b)*4;
    const double w0 = zp[0], w1 = zp[1], w2 = zp[2], w3 = zp[3];
    const double* Hf = H + (size_t)f*LF*4;
    float* ycol = Pt + 64 + (size_t)f*64 + b;
    const int kk_top = LF*q + 85;
    const int n      = (bq < NSEG-1) ? LF : 86;
    #pragma unroll 4
    for (int jb = 0; jb < n; ++jb) {
        const int kk = kk_top - jb;
        double corr = Hf[jb*4+0]*w0 + Hf[jb*4+1]*w1 + Hf[jb*4+2]*w2 + Hf[jb*4+3]*w3;
        float* d = &ycol[(size_t)kk*SEQ];
        *d = (float)((double)*d + corr);
    }
}
#undef FSTEP
#undef COEFS

// ---------------- Kernel 2a: split-K GEMM partials (8x8 tile, pipelined) --
__global__ __launch_bounds__(256) void k_ugemm(
    const float* __restrict__ Pt, const float* __restrict__ W1,
    float* __restrict__ Up)
{
    __shared__ float As[2][16*128];
    __shared__ float Bs[2][16*128];
    const int tid = threadIdx.x;
    const int rq = blockIdx.x, hq = blockIdx.y, ks = blockIdx.z;
    const int r0 = rq*128, h0 = hq*128;
    const int tg = tid & 15, ig = tid >> 4;
    const int wv = tid >> 6, lane = tid & 63;
    const int rowoff = lane >> 5;
    int colA = r0 + (lane & 31)*4; if (colA > SEQ-4) colA = SEQ-4;
    const int colB = h0 + (lane & 31)*4;

    float acc[8][8] = {};

#define STAGE_UG(cc, bf) { \
        const int k0s = ks*KPB + (cc)*KC2; \
        _Pragma("unroll") \
        for (int q = 0; q < 2; ++q) { \
            int j = wv + 4*q; \
            int r = 2*j + rowoff; if (r > 14) r = 14; \
            gload16(Pt + (size_t)(k0s+r)*SEQ + colA, &As[bf][j*256]); \
            gload16(W1 + (size_t)(k0s+r)*NH + colB, &Bs[bf][j*256]); \
        } }

    STAGE_UG(0, 0);
    __syncthreads();
    int cur = 0;
    for (int c = 0; c < KPB/KC2; ++c) {       // 20 chunks of 15 k
        if (c + 1 < KPB/KC2) STAGE_UG(c + 1, cur ^ 1);
        #pragma unroll 5
        for (int k = 0; k < KC2; ++k) {
            float4 alo = *(const float4*)&As[cur][k*128 + tg*4];
            float4 ahi = *(const float4*)&As[cur][k*128 + 64 + tg*4];
            float4 blo = *(const float4*)&Bs[cur][k*128 + ig*4];
            float4 bhi = *(const float4*)&Bs[cur][k*128 + 64 + ig*4];
            float a[8] = {alo.x,alo.y,alo.z,alo.w,ahi.x,ahi.y,ahi.z,ahi.w};
            float b[8] = {blo.x,blo.y,blo.z,blo.w,bhi.x,bhi.y,bhi.z,bhi.w};
            #pragma unroll
            for (int mt = 0; mt < 8; ++mt)
                #pragma unroll
                for (int nn = 0; nn < 8; ++nn)
                    acc[mt][nn] = fmaf(a[mt], b[nn], acc[mt][nn]);
        }
        __syncthreads();
        cur ^= 1;
    }
#undef STAGE_UG

    float* up = Up + (size_t)ks*UPROWS*NH;
    #pragma unroll
    for (int mt = 0; mt < 8; ++mt) {
        const int r = r0 + (mt>>2)*64 + tg*4 + (mt&3);
        if (r < SEQ) {
            *(float4*)&up[(size_t)r*NH + h0 + ig*4]
                = make_float4(acc[mt][0], acc[mt][1], acc[mt][2], acc[mt][3]);
            *(float4*)&up[(size_t)r*NH + h0 + 64 + ig*4]
                = make_float4(acc[mt][4], acc[mt][5], acc[mt][6], acc[mt][7]);
        }
    }
}

// ---------------- k_uvred: reduce partials + tanh-deriv + V-build + T -----
__global__ __launch_bounds__(256) void k_uvred(
    const float* __restrict__ Up, const float* __restrict__ b1,
    const float* __restrict__ w2, const int* __restrict__ freq_index,
    float* __restrict__ Vt)
{
    __shared__ float Vtile[32][257];
    const int n0 = blockIdx.x * 32;      // 200 blocks
    const int h  = threadIdx.x;
    const float b1v = b1[h], w2v = w2[h];
    const float thp = tanhf(b1v);
    const float upseudo = (1.f - thp*thp) * w2v;
    for (int r = 0; r < 32; ++r) {
        int np = n0 + r;
        int bb = np / 100, jj = np - bb*100;
        int ii = freq_index[jj];
        int ra = (ii <= 2) ? bb : 64 + (ii-3)*64 + bb;
        float sa = Up[(size_t)ra*NH + h];
        #pragma unroll
        for (int ks = 1; ks < KS; ++ks)
            sa += Up[(size_t)ks*UPROWS*NH + (size_t)ra*NH + h];
        float ta = tanhf(sa + b1v);
        float ua = (1.f - ta*ta) * w2v;
        float ub;
        if (ii >= 99) ub = upseudo;
        else {
            int rb = (ii <= 1) ? bb : 64 + (ii-2)*64 + bb;
            float sb = Up[(size_t)rb*NH + h];
            #pragma unroll
            for (int ks = 1; ks < KS; ++ks)
                sb += Up[(size_t)ks*UPROWS*NH + (size_t)rb*NH + h];
            float tb_ = tanhf(sb + b1v);
            ub = (1.f - tb_*tb_) * w2v;
        }
        Vtile[r][h] = 0.5f*(ua + ub);
    }
    __syncthreads();
    const int ln = threadIdx.x & 31;
    const int hg = threadIdx.x >> 5;     // 0..7 -> 32 h each
    for (int m = 0; m < 32; ++m) {
        int hh = hg*32 + m;
        Vt[(size_t)hh*VTS + n0 + ln] = Vtile[ln][hh];
    }
}

// ---------------- k_delta: delta -> d_out via LDS-staged Pt row -----------
__global__ __launch_bounds__(256) void k_delta(
    const float* __restrict__ Pt, const int* __restrict__ freq_index,
    float* __restrict__ out)
{
    __shared__ float Lv[99*65];
    __shared__ int fx[NI];
    const int t   = blockIdx.x;          // 0..2999
    const int tid = threadIdx.x;
    if (tid < NI) fx[tid] = freq_index[tid];
    const float* ptrow = Pt + (size_t)t*SEQ;
    for (int c4 = tid; c4 < SEQ/4; c4 += 256) {     // 1584 float4
        float4 v = *(const float4*)(ptrow + c4*4);
        const int j  = c4 >> 4;
        const int bb = (c4 & 15) << 2;
        float* dst = &Lv[j*65 + bb];
        dst[0] = v.x; dst[1] = v.y; dst[2] = v.z; dst[3] = v.w;
    }
    __syncthreads();
    for (int q = tid; q < 1600; q += 256) {
        const int bb = q / 25, f4 = q - bb*25;
        float v[4];
        #pragma unroll
        for (int k = 0; k < 4; ++k) {
            const int ii = fx[f4*4 + k];
            const int ja = (ii <= 2) ? 0 : (ii - 2);
            float rv = Lv[ja*65 + bb];
            float rvn;
            if (ii >= 99) rvn = 0.f;
            else {
                const int jb = (ii <= 1) ? 0 : (ii - 1);
                rvn = Lv[jb*65 + bb];
            }
            v[k] = rv - rvn;
        }
        *(float4*)&out[(size_t)bb*T_LEN*NI + (size_t)t*NI + f4*4]
            = make_float4(v[0], v[1], v[2], v[3]);
    }
}

// ---------------- Kernel 3: GEMM (8x8 tile, pipelined) + RMW epilogue -----
__global__ __launch_bounds__(256) void k_out(
    const float* __restrict__ W1T, const float* __restrict__ Vt,
    float* __restrict__ out)
{
    __shared__ float As[2][16*128];
    __shared__ float Vs[2][16*128];
    const int tid = threadIdx.x;
    const int tb  = blockIdx.x;     // 0..23
    const int nb  = blockIdx.y;     // 0..49

    const int tg = tid & 15;
    const int ig = tid >> 4;
    const int t0 = tb*128, n0 = nb*128;
    const int wv = tid >> 6, lane = tid & 63;
    const int rowoff = lane >> 5;
    const int coloff = (lane & 31)*4;

    const int npA = n0 + ig*4;
    const int bbA = npA / 100, jjA = npA - bbA*100;
    const int npB = npA + 64;
    const int bbB = npB / 100, jjB = npB - bbB*100;

    float acc[8][8] = {};

#define STAGE_KO(cc, bf) { \
        const int k0s = (cc)*KCO; \
        _Pragma("unroll") \
        for (int q = 0; q < 2; ++q) { \
            int j = wv + 4*q; \
            int r = 2*j + rowoff; \
            gload16(W1T + (size_t)(k0s+r)*WTS + t0 + coloff, &As[bf][j*256]); \
            gload16(Vt  + (size_t)(k0s+r)*VTS + n0 + coloff, &Vs[bf][j*256]); \
        } }

    STAGE_KO(0, 0);
    __syncthreads();
    int cur = 0;
    for (int c = 0; c < 16; ++c) {
        if (c + 1 < 16) STAGE_KO(c + 1, cur ^ 1);
        #pragma unroll 4
        for (int k = 0; k < KCO; ++k) {
            float4 alo = *(const float4*)&As[cur][k*128 + tg*4];
            float4 ahi = *(const float4*)&As[cur][k*128 + 64 + tg*4];
            float4 vlo = *(const float4*)&Vs[cur][k*128 + ig*4];
            float4 vhi = *(const float4*)&Vs[cur][k*128 + 64 + ig*4];
            float a[8] = {alo.x, alo.y, alo.z, alo.w, ahi.x, ahi.y, ahi.z, ahi.w};
            float v[8] = {vlo.x, vlo.y, vlo.z, vlo.w, vhi.x, vhi.y, vhi.z, vhi.w};
            #pragma unroll
            for (int mt = 0; mt < 8; ++mt)
                #pragma unroll
                for (int nn = 0; nn < 8; ++nn)
                    acc[mt][nn] = fmaf(a[mt], v[nn], acc[mt][nn]);
        }
        __syncthreads();
        cur ^= 1;
    }
#undef STAGE_KO

    #pragma unroll
    for (int mt = 0; mt < 8; ++mt) {
        const int t = t0 + (mt>>2)*64 + tg*4 + (mt&3);
        if (t < T_LEN) {
            float* oA = &out[(size_t)bbA*T_LEN*NI + (size_t)t*NI + jjA];
            float4 dA = *(const float4*)oA;
            *(float4*)oA = make_float4(acc[mt][0]*dA.x, acc[mt][1]*dA.y,
                                       acc[mt][2]*dA.z, acc[mt][3]*dA.w);
            float* oB = &out[(size_t)bbB*T_LEN*NI + (size_t)t*NI + jjB];
            float4 dB = *(const float4*)oB;
            *(float4*)oB = make_float4(acc[mt][4]*dB.x, acc[mt][5]*dB.y,
                                       acc[mt][6]*dB.z, acc[mt][7]*dB.w);
        }
    }
}

extern "C" void kernel_launch(void* const* d_in, const int* in_sizes, int n_in,
                              void* d_out, int out_size, void* d_ws, size_t ws_size,
                              hipStream_t stream) {
    const float* x      = (const float*)d_in[0];
    const float* b_all  = (const float*)d_in[1];
    const float* a_all  = (const float*)d_in[2];
    const float* zi_all = (const float*)d_in[3];
    const float* W1     = (const float*)d_in[4];
    const float* b1     = (const float*)d_in[5];
    const float* w2     = (const float*)d_in[6];
    const int*   fidx   = (const int*)d_in[7];
    float* out = (float*)d_out;

    float* Pt  = (float*)d_ws;                      // [3000][6336] k-major (76.0MB)
    float* Vt  = Pt + (size_t)T_LEN * SEQ;          // [256][6400] (6.55MB)
    float* W1T = Vt + (size_t)NH * VTS;             // [256][3072] (3.15MB) => 85.7MB

    // filtfilt scratch lives in d_out (consumed before k_ugemm reuses it)
    double* Hd  = (double*)d_out;                   // [97][101][4]
    double* Mfd = Hd + (size_t)NF*LF*4;             // [97][16]
    double* Zef = Mfd + NF*16;                      // [97][30][64][4]
    double* Zeb = Zef + (size_t)NF*NSEG*64*4;
    double* Zfd = Zeb + (size_t)NF*NSEG*64*4;
    double* Zbd = Zfd + (size_t)NF*NSEG*64*4;
    float*  YRb = (float*)(Zbd + (size_t)NF*NSEG*64*4);   // [97][15][64]
    float*  Up  = out;                              // split-K partials (65.5 MB)

    hipLaunchKernelGGL(k_init, dim3(246), dim3(256), 0, stream,
                       x, W1, a_all, Pt, W1T, Hd, Mfd);
    hipLaunchKernelGGL(k_seg_fwd, dim3(NF, NSEG), dim3(64), 0, stream,
                       Pt, b_all, a_all, zi_all, YRb, Zef);
    hipLaunchKernelGGL(k_stitch, dim3(NF), dim3(64), 0, stream,
                       Zef, Mfd, Zfd);
    hipLaunchKernelGGL(k_seg_bwd, dim3(NF, NSEG), dim3(64), 0, stream,
                       Pt, b_all, a_all, zi_all, YRb, Hd, Zfd, Zeb);
    hipLaunchKernelGGL(k_stitch, dim3(NF), dim3(64), 0, stream,
                       Zeb, Mfd, Zbd);
    hipLaunchKernelGGL(k_corr_bwd, dim3(NF, NSEG-1), dim3(64), 0, stream,
                       Pt, Hd, Zbd);
    hipLaunchKernelGGL(k_ugemm, dim3(50, 2, KS), dim3(256), 0, stream,
                       Pt, W1, Up);
    hipLaunchKernelGGL(k_uvred, dim3(UPROWS/32), dim3(256), 0, stream,
                       Up, b1, w2, fidx, Vt);
    hipLaunchKernelGGL(k_delta, dim3(T_LEN), dim3(256), 0, stream,
                       Pt, fidx, out);
    hipLaunchKernelGGL(k_out, dim3((T_LEN+127)/128, (NB*NI)/128), dim3(256), 0, stream,
                       W1T, Vt, out);
}

// Round 24
// 430.185 us; speedup vs baseline: 1.0248x; 1.0248x over previous
//
#include <hip/hip_runtime.h>
#include <math.h>

#define T_LEN 3000
#define NF 97
#define NB 64
#define NH 256
#define NI 100
#define SEQ 6336       // Pt row width: 64 x-cols + 6208 filter cols
#define KCO 16         // k_out K-chunk (16 chunks of 16)
#define KS 10          // k_ugemm split-K factor
#define KPB 300        // k per split = 3000/KS
#define KC2 15         // k_ugemm K-chunk (20 chunks of 15)
#define UPROWS 6400
#define LF 202         // segment length (15*202 = 3030 ext samples)
#define NSEG 15
#define WTS 3072       // W1T row stride (t padded to 3072)
#define VTS 6400       // Vt row stride

__device__ __forceinline__ void gload16(const float* g, float* l) {
    __builtin_amdgcn_global_load_lds(
        (const __attribute__((address_space(1))) void*)g,
        (__attribute__((address_space(3))) void*)l, 16, 0, 0);
}

// ---------------- k_init: merged prep (x^T) + W1 transpose + hom table ----
__global__ __launch_bounds__(256) void k_init(
    const float* __restrict__ x, const float* __restrict__ W1,
    const float* __restrict__ a_all, float* __restrict__ Pt,
    float* __restrict__ W1T, double* __restrict__ H, double* __restrict__ Mfd)
{
    const int blk = blockIdx.x;
    if (blk < 47) {                       // ---- prep
        const int kk0 = blk * 64;
        const int b   = threadIdx.x & 63;
        const int ko  = threadIdx.x >> 6;
        #pragma unroll
        for (int p = 0; p < 16; ++p) {
            int kk = kk0 + ko + 4*p;
            if (kk < T_LEN) Pt[(size_t)kk*SEQ + b] = x[(size_t)b*T_LEN + kk];
        }
    } else if (blk < 239) {               // ---- W1 -> W1T (48 x 4 tiles)
        __shared__ float tile[64][65];
        const int w  = blk - 47;
        const int tb = w % 48;
        const int hb = w / 48;
        const int lt = threadIdx.x & 63, lw = threadIdx.x >> 6;
        #pragma unroll
        for (int i = 0; i < 16; ++i) {
            int t = tb*64 + lw*16 + i; if (t > T_LEN-1) t = T_LEN-1;
            tile[lw*16+i][lt] = W1[(size_t)t*NH + hb*64 + lt];
        }
        __syncthreads();
        #pragma unroll
        for (int i = 0; i < 16; ++i) {
            int h = hb*64 + lw*16 + i;
            W1T[(size_t)h*WTS + tb*64 + lt] = tile[lt][lw*16+i];
        }
    } else {                              // ---- hom: H[f][j][i], M^202
        if (threadIdx.x >= 64) return;
        const int ft = (blk - 239)*64 + threadIdx.x;
        const int f = ft >> 2, ib = ft & 3;
        if (f >= NF) return;
        const double a1 = a_all[f*5+1], a2 = a_all[f*5+2],
                     a3 = a_all[f*5+3], a4 = a_all[f*5+4];
        double z0 = (ib==0), z1 = (ib==1), z2 = (ib==2), z3 = (ib==3);
        for (int j = 0; j <= LF; ++j) {
            if (j < LF) H[((size_t)f*LF + j)*4 + ib] = z0;
            if (j == LF) {
                Mfd[f*16 + 0*4 + ib] = z0; Mfd[f*16 + 1*4 + ib] = z1;
                Mfd[f*16 + 2*4 + ib] = z2; Mfd[f*16 + 3*4 + ib] = z3;
                break;
            }
            double yv = z0;
            z0 = z1 - a1*yv; z1 = z2 - a2*yv; z2 = z3 - a3*yv; z3 = -a4*yv;
        }
    }
}

#define COEFS \
    const double bc0 = b_all[f*5+0], bc1 = b_all[f*5+1], bc2 = b_all[f*5+2], \
                 bc3 = b_all[f*5+3], bc4 = b_all[f*5+4]; \
    const double ac1 = a_all[f*5+1], ac2 = a_all[f*5+2], \
                 ac3 = a_all[f*5+3], ac4 = a_all[f*5+4];

#define FSTEP(XV, DST) { double xv = (XV); \
    double yv = fma(bc0, xv, z0); \
    z0 = fma(bc1, xv, z1) - ac1*yv; \
    z1 = fma(bc2, xv, z2) - ac2*yv; \
    z2 = fma(bc3, xv, z3) - ac3*yv; \
    z3 = bc4*xv - ac4*yv; \
    DST = (float)yv; }

// ---------------- k_seg_fwd: zero-state forward pass per segment ----------
__global__ __launch_bounds__(64) void k_seg_fwd(
    float* Pt, const float* __restrict__ b_all, const float* __restrict__ a_all,
    const float* __restrict__ zi_all, float* __restrict__ YRb,
    double* __restrict__ Zef)
{
    const int f = blockIdx.x, p = blockIdx.y, b = threadIdx.x;
    COEFS
    const float* xc = Pt + b;
    float* ycol = Pt + 64 + (size_t)f*64 + b;
    double z0 = 0, z1 = 0, z2 = 0, z3 = 0;

    if (p == 0) {
        const double x0 = (double)xc[0];
        const double e0 = 2.0*x0 - (double)xc[(size_t)15*SEQ];
        z0 = (double)zi_all[f*4+0]*e0; z1 = (double)zi_all[f*4+1]*e0;
        z2 = (double)zi_all[f*4+2]*e0; z3 = (double)zi_all[f*4+3]*e0;
        float le[15];
        #pragma unroll
        for (int i = 0; i < 15; ++i) le[i] = xc[(size_t)(15-i)*SEQ];
        #pragma unroll
        for (int i = 0; i < 15; ++i) { float o; FSTEP(2.0*x0 - (double)le[i], o); (void)o; }
    }
    int kk0, n;
    if (p == 0)       { kk0 = 0;          n = 187; }
    else if (p < 14)  { kk0 = p*LF - 15;  n = LF;  }
    else              { kk0 = 2813;       n = 187; }

    {
        const int nc = n/20, rem = n - nc*20;
        float A[20], B[20], C[20];
#define LDF(BUF, c) { _Pragma("unroll") \
        for (int j = 0; j < 20; ++j) BUF[j] = xc[(size_t)(kk0+(c)*20+j)*SEQ]; }
#define CHF(BUF, c) { _Pragma("unroll") \
        for (int j = 0; j < 20; ++j) { float o; FSTEP((double)BUF[j], o); \
            ycol[(size_t)(kk0+(c)*20+j)*SEQ] = o; } }
        if (nc > 0) LDF(A, 0); if (nc > 1) LDF(B, 1); if (nc > 2) LDF(C, 2);
        for (int g = 0; g < nc; g += 3) {
            CHF(A, g); if (g+3 < nc) LDF(A, g+3);
            if (g+1 < nc) { CHF(B, g+1); if (g+4 < nc) LDF(B, g+4); }
            if (g+2 < nc) { CHF(C, g+2); if (g+5 < nc) LDF(C, g+5); }
        }
        if (rem) {
            float T[19];
            #pragma unroll
            for (int j = 0; j < 19; ++j) if (j < rem) T[j] = xc[(size_t)(kk0+nc*20+j)*SEQ];
            #pragma unroll
            for (int j = 0; j < 19; ++j) if (j < rem) {
                float o; FSTEP((double)T[j], o); ycol[(size_t)(kk0+nc*20+j)*SEQ] = o;
            }
        }
#undef LDF
#undef CHF
    }
    if (p == 14) {
        const double xl = (double)xc[(size_t)(T_LEN-1)*SEQ];
        float re[15];
        #pragma unroll
        for (int i = 0; i < 15; ++i) re[i] = xc[(size_t)(2998-i)*SEQ];
        #pragma unroll
        for (int i = 0; i < 15; ++i) {
            float o; FSTEP(2.0*xl - (double)re[i], o);
            YRb[((size_t)f*15 + i)*64 + b] = o;
        }
    }
    double* ze = Zef + (((size_t)f*NSEG + p)*64 + b)*4;
    ze[0] = z0; ze[1] = z1; ze[2] = z2; ze[3] = z3;
}

// ---------------- k_stitch: boundary-state recurrence (M = M^202) ---------
__global__ __launch_bounds__(64) void k_stitch(
    const double* __restrict__ Ze, const double* __restrict__ Mm,
    double* __restrict__ Zo)
{
    const int f = blockIdx.x, b = threadIdx.x;
    double m[16];
    #pragma unroll
    for (int r = 0; r < 16; ++r) m[r] = Mm[f*16 + r];
    const double* z0p = Ze + (((size_t)f*NSEG + 0)*64 + b)*4;
    double z0 = z0p[0], z1 = z0p[1], z2 = z0p[2], z3 = z0p[3];
    {   double* o = Zo + (((size_t)f*NSEG + 1)*64 + b)*4;
        o[0]=z0; o[1]=z1; o[2]=z2; o[3]=z3; }
    for (int p = 1; p <= 13; ++p) {
        const double* zep = Ze + (((size_t)f*NSEG + p)*64 + b)*4;
        double n0 = zep[0] + m[0]*z0  + m[1]*z1  + m[2]*z2  + m[3]*z3;
        double n1 = zep[1] + m[4]*z0  + m[5]*z1  + m[6]*z2  + m[7]*z3;
        double n2 = zep[2] + m[8]*z0  + m[9]*z1  + m[10]*z2 + m[11]*z3;
        double n3 = zep[3] + m[12]*z0 + m[13]*z1 + m[14]*z2 + m[15]*z3;
        z0 = n0; z1 = n1; z2 = n2; z3 = n3;
        double* o = Zo + (((size_t)f*NSEG + p + 1)*64 + b)*4;
        o[0]=z0; o[1]=z1; o[2]=z2; o[3]=z3;
    }
}

// ---------------- k_seg_bwd: 202-aligned bwd segments, fwd-corr fused -----
__global__ __launch_bounds__(64) void k_seg_bwd(
    float* Pt, const float* __restrict__ b_all, const float* __restrict__ a_all,
    const float* __restrict__ zi_all, const float* __restrict__ YRb,
    const double* __restrict__ H, const double* __restrict__ Zf,
    double* __restrict__ Zeb)
{
    const int f = blockIdx.x, bq = blockIdx.y, b = threadIdx.x;
    COEFS
    const int q = 14 - bq;
    float* ycol = Pt + 64 + (size_t)f*64 + b;
    const float* yrp = YRb + (size_t)f*15*64 + b;
    const double* Hf = H + (size_t)f*LF*4;
    double w0 = 0, w1 = 0, w2 = 0, w3 = 0;
    if (q >= 1) {
        const double* zp = Zf + (((size_t)f*NSEG + q)*64 + b)*4;
        w0 = zp[0]; w1 = zp[1]; w2 = zp[2]; w3 = zp[3];
    }
    double z0 = 0, z1 = 0, z2 = 0, z3 = 0;

#define CORR(J) (Hf[(J)*4+0]*w0 + Hf[(J)*4+1]*w1 + Hf[(J)*4+2]*w2 + Hf[(J)*4+3]*w3)

    if (bq == 0) {
        const float ylf = (float)((double)yrp[14*64] + CORR(201));
        const double yl = (double)ylf;
        z0 = (double)zi_all[f*4+0]*yl; z1 = (double)zi_all[f*4+1]*yl;
        z2 = (double)zi_all[f*4+2]*yl; z3 = (double)zi_all[f*4+3]*yl;
        float t15[15];
        #pragma unroll
        for (int i = 0; i < 15; ++i)
            t15[i] = (float)((double)yrp[(size_t)(14-i)*64] + CORR(201-i));
        #pragma unroll
        for (int i = 0; i < 15; ++i) { float o; FSTEP((double)t15[i], o); (void)o; }
    }
    const int kkH  = (bq == 0) ? 2999 : 202*q + 186;
    const int n    = (bq == 0 || bq == 14) ? 187 : 202;
    const int joff = 15 - 202*q;

    {
        const int nc = n/20, rem = n - nc*20;
        float A[20], B[20], C[20];
#define LDBc(BUF, c) { _Pragma("unroll") \
        for (int j = 0; j < 20; ++j) { \
            const int kk = kkH-19-20*(c)+j; \
            BUF[j] = (float)((double)ycol[(size_t)kk*SEQ] + CORR(kk + joff)); } }
#define CHBc(BUF, c) { _Pragma("unroll") \
        for (int j = 19; j >= 0; --j) { float o; FSTEP((double)BUF[j], o); BUF[j] = o; } \
        _Pragma("unroll") \
        for (int j = 0; j < 20; ++j) ycol[(size_t)(kkH-19-20*(c)+j)*SEQ] = BUF[j]; }
        if (nc > 0) LDBc(A, 0); if (nc > 1) LDBc(B, 1); if (nc > 2) LDBc(C, 2);
        for (int g = 0; g < nc; g += 3) {
            CHBc(A, g); if (g+3 < nc) LDBc(A, g+3);
            if (g+1 < nc) { CHBc(B, g+1); if (g+4 < nc) LDBc(B, g+4); }
            if (g+2 < nc) { CHBc(C, g+2); if (g+5 < nc) LDBc(C, g+5); }
        }
        if (rem) {
            float T[19];
            #pragma unroll
            for (int j = 0; j < 19; ++j) if (j < rem) {
                const int kk = kkH - 20*nc - j;
                T[j] = (float)((double)ycol[(size_t)kk*SEQ] + CORR(kk + joff));
            }
            #pragma unroll
            for (int j = 0; j < 19; ++j) if (j < rem) {
                float o; FSTEP((double)T[j], o); ycol[(size_t)(kkH-20*nc-j)*SEQ] = o;
            }
        }
#undef LDBc
#undef CHBc
    }
#undef CORR
    double* ze = Zeb + (((size_t)f*NSEG + bq)*64 + b)*4;
    ze[0] = z0; ze[1] = z1; ze[2] = z2; ze[3] = z3;
}

// ---------------- k_corr_bwd: aligned blocks bq = 1..14 -------------------
__global__ __launch_bounds__(64) void k_corr_bwd(
    float* Pt, const double* __restrict__ H, const double* __restrict__ Zb)
{
    const int f = blockIdx.x, bq = blockIdx.y + 1, b = threadIdx.x;
    const int q = 14 - bq;
    const double* zp = Zb + (((size_t)f*NSEG + bq)*64 + b)*4;
    const double w0 = zp[0], w1 = zp[1], w2 = zp[2], w3 = zp[3];
    const double* Hf = H + (size_t)f*LF*4;
    float* ycol = Pt + 64 + (size_t)f*64 + b;
    const int kk_top = (bq < 14) ? 202*q + 186 : 186;
    const int n      = (bq < 14) ? 202 : 187;
    #pragma unroll 4
    for (int jb = 0; jb < n; ++jb) {
        const int kk = kk_top - jb;
        double corr = Hf[jb*4+0]*w0 + Hf[jb*4+1]*w1 + Hf[jb*4+2]*w2 + Hf[jb*4+3]*w3;
        float* d = &ycol[(size_t)kk*SEQ];
        *d = (float)((double)*d + corr);
    }
}
#undef FSTEP
#undef COEFS

// ---------------- Kernel 2a: split-K GEMM partials (8x8 tile, pipelined) --
__global__ __launch_bounds__(256) void k_ugemm(
    const float* __restrict__ Pt, const float* __restrict__ W1,
    float* __restrict__ Up)
{
    __shared__ float As[2][16*128];
    __shared__ float Bs[2][16*128];
    const int tid = threadIdx.x;
    const int rq = blockIdx.x, hq = blockIdx.y, ks = blockIdx.z;
    const int r0 = rq*128, h0 = hq*128;
    const int tg = tid & 15, ig = tid >> 4;
    const int wv = tid >> 6, lane = tid & 63;
    const int rowoff = lane >> 5;
    int colA = r0 + (lane & 31)*4; if (colA > SEQ-4) colA = SEQ-4;
    const int colB = h0 + (lane & 31)*4;

    float acc[8][8] = {};

#define STAGE_UG(cc, bf) { \
        const int k0s = ks*KPB + (cc)*KC2; \
        _Pragma("unroll") \
        for (int q = 0; q < 2; ++q) { \
            int j = wv + 4*q; \
            int r = 2*j + rowoff; if (r > 14) r = 14; \
            gload16(Pt + (size_t)(k0s+r)*SEQ + colA, &As[bf][j*256]); \
            gload16(W1 + (size_t)(k0s+r)*NH + colB, &Bs[bf][j*256]); \
        } }

    STAGE_UG(0, 0);
    __syncthreads();
    int cur = 0;
    for (int c = 0; c < KPB/KC2; ++c) {       // 20 chunks of 15 k
        if (c + 1 < KPB/KC2) STAGE_UG(c + 1, cur ^ 1);
        #pragma unroll 5
        for (int k = 0; k < KC2; ++k) {
            float4 alo = *(const float4*)&As[cur][k*128 + tg*4];
            float4 ahi = *(const float4*)&As[cur][k*128 + 64 + tg*4];
            float4 blo = *(const float4*)&Bs[cur][k*128 + ig*4];
            float4 bhi = *(const float4*)&Bs[cur][k*128 + 64 + ig*4];
            float a[8] = {alo.x,alo.y,alo.z,alo.w,ahi.x,ahi.y,ahi.z,ahi.w};
            float b[8] = {blo.x,blo.y,blo.z,blo.w,bhi.x,bhi.y,bhi.z,bhi.w};
            #pragma unroll
            for (int mt = 0; mt < 8; ++mt)
                #pragma unroll
                for (int nn = 0; nn < 8; ++nn)
                    acc[mt][nn] = fmaf(a[mt], b[nn], acc[mt][nn]);
        }
        __syncthreads();
        cur ^= 1;
    }
#undef STAGE_UG

    float* up = Up + (size_t)ks*UPROWS*NH;
    #pragma unroll
    for (int mt = 0; mt < 8; ++mt) {
        const int r = r0 + (mt>>2)*64 + tg*4 + (mt&3);
        if (r < SEQ) {
            *(float4*)&up[(size_t)r*NH + h0 + ig*4]
                = make_float4(acc[mt][0], acc[mt][1], acc[mt][2], acc[mt][3]);
            *(float4*)&up[(size_t)r*NH + h0 + 64 + ig*4]
                = make_float4(acc[mt][4], acc[mt][5], acc[mt][6], acc[mt][7]);
        }
    }
}

// ---------------- k_uvred: reduce partials + tanh-deriv + V-build + T -----
__global__ __launch_bounds__(256) void k_uvred(
    const float* __restrict__ Up, const float* __restrict__ b1,
    const float* __restrict__ w2, const int* __restrict__ freq_index,
    float* __restrict__ Vt)
{
    __shared__ float Vtile[32][257];
    const int n0 = blockIdx.x * 32;      // 200 blocks
    const int h  = threadIdx.x;
    const float b1v = b1[h], w2v = w2[h];
    const float thp = tanhf(b1v);
    const float upseudo = (1.f - thp*thp) * w2v;
    for (int r = 0; r < 32; ++r) {
        int np = n0 + r;
        int bb = np / 100, jj = np - bb*100;
        int ii = freq_index[jj];
        int ra = (ii <= 2) ? bb : 64 + (ii-3)*64 + bb;
        float sa = Up[(size_t)ra*NH + h];
        #pragma unroll
        for (int ks = 1; ks < KS; ++ks)
            sa += Up[(size_t)ks*UPROWS*NH + (size_t)ra*NH + h];
        float ta = tanhf(sa + b1v);
        float ua = (1.f - ta*ta) * w2v;
        float ub;
        if (ii >= 99) ub = upseudo;
        else {
            int rb = (ii <= 1) ? bb : 64 + (ii-2)*64 + bb;
            float sb = Up[(size_t)rb*NH + h];
            #pragma unroll
            for (int ks = 1; ks < KS; ++ks)
                sb += Up[(size_t)ks*UPROWS*NH + (size_t)rb*NH + h];
            float tb_ = tanhf(sb + b1v);
            ub = (1.f - tb_*tb_) * w2v;
        }
        Vtile[r][h] = 0.5f*(ua + ub);
    }
    __syncthreads();
    const int ln = threadIdx.x & 31;
    const int hg = threadIdx.x >> 5;     // 0..7 -> 32 h each
    for (int m = 0; m < 32; ++m) {
        int hh = hg*32 + m;
        Vt[(size_t)hh*VTS + n0 + ln] = Vtile[ln][hh];
    }
}

// ---------------- k_delta: delta -> d_out via LDS-staged Pt row -----------
__global__ __launch_bounds__(256) void k_delta(
    const float* __restrict__ Pt, const int* __restrict__ freq_index,
    float* __restrict__ out)
{
    __shared__ float Lv[99*65];
    __shared__ int fx[NI];
    const int t   = blockIdx.x;          // 0..2999
    const int tid = threadIdx.x;
    if (tid < NI) fx[tid] = freq_index[tid];
    const float* ptrow = Pt + (size_t)t*SEQ;
    for (int c4 = tid; c4 < SEQ/4; c4 += 256) {     // 1584 float4
        float4 v = *(const float4*)(ptrow + c4*4);
        const int j  = c4 >> 4;
        const int bb = (c4 & 15) << 2;
        float* dst = &Lv[j*65 + bb];
        dst[0] = v.x; dst[1] = v.y; dst[2] = v.z; dst[3] = v.w;
    }
    __syncthreads();
    for (int q = tid; q < 1600; q += 256) {
        const int bb = q / 25, f4 = q - bb*25;
        float v[4];
        #pragma unroll
        for (int k = 0; k < 4; ++k) {
            const int ii = fx[f4*4 + k];
            const int ja = (ii <= 2) ? 0 : (ii - 2);
            float rv = Lv[ja*65 + bb];
            float rvn;
            if (ii >= 99) rvn = 0.f;
            else {
                const int jb = (ii <= 1) ? 0 : (ii - 1);
                rvn = Lv[jb*65 + bb];
            }
            v[k] = rv - rvn;
        }
        *(float4*)&out[(size_t)bb*T_LEN*NI + (size_t)t*NI + f4*4]
            = make_float4(v[0], v[1], v[2], v[3]);
    }
}

// ---------------- Kernel 3: GEMM (8x8 tile, pipelined) + RMW epilogue -----
__global__ __launch_bounds__(256) void k_out(
    const float* __restrict__ W1T, const float* __restrict__ Vt,
    float* __restrict__ out)
{
    __shared__ float As[2][16*128];
    __shared__ float Vs[2][16*128];
    const int tid = threadIdx.x;
    const int tb  = blockIdx.x;     // 0..23
    const int nb  = blockIdx.y;     // 0..49

    const int tg = tid & 15;
    const int ig = tid >> 4;
    const int t0 = tb*128, n0 = nb*128;
    const int wv = tid >> 6, lane = tid & 63;
    const int rowoff = lane >> 5;
    const int coloff = (lane & 31)*4;

    const int npA = n0 + ig*4;
    const int bbA = npA / 100, jjA = npA - bbA*100;
    const int npB = npA + 64;
    const int bbB = npB / 100, jjB = npB - bbB*100;

    float acc[8][8] = {};

#define STAGE_KO(cc, bf) { \
        const int k0s = (cc)*KCO; \
        _Pragma("unroll") \
        for (int q = 0; q < 2; ++q) { \
            int j = wv + 4*q; \
            int r = 2*j + rowoff; \
            gload16(W1T + (size_t)(k0s+r)*WTS + t0 + coloff, &As[bf][j*256]); \
            gload16(Vt  + (size_t)(k0s+r)*VTS + n0 + coloff, &Vs[bf][j*256]); \
        } }

    STAGE_KO(0, 0);
    __syncthreads();
    int cur = 0;
    for (int c = 0; c < 16; ++c) {
        if (c + 1 < 16) STAGE_KO(c + 1, cur ^ 1);
        #pragma unroll 4
        for (int k = 0; k < KCO; ++k) {
            float4 alo = *(const float4*)&As[cur][k*128 + tg*4];
            float4 ahi = *(const float4*)&As[cur][k*128 + 64 + tg*4];
            float4 vlo = *(const float4*)&Vs[cur][k*128 + ig*4];
            float4 vhi = *(const float4*)&Vs[cur][k*128 + 64 + ig*4];
            float a[8] = {alo.x, alo.y, alo.z, alo.w, ahi.x, ahi.y, ahi.z, ahi.w};
            float v[8] = {vlo.x, vlo.y, vlo.z, vlo.w, vhi.x, vhi.y, vhi.z, vhi.w};
            #pragma unroll
            for (int mt = 0; mt < 8; ++mt)
                #pragma unroll
                for (int nn = 0; nn < 8; ++nn)
                    acc[mt][nn] = fmaf(a[mt], v[nn], acc[mt][nn]);
        }
        __syncthreads();
        cur ^= 1;
    }
#undef STAGE_KO

    #pragma unroll
    for (int mt = 0; mt < 8; ++mt) {
        const int t = t0 + (mt>>2)*64 + tg*4 + (mt&3);
        if (t < T_LEN) {
            float* oA = &out[(size_t)bbA*T_LEN*NI + (size_t)t*NI + jjA];
            float4 dA = *(const float4*)oA;
            *(float4*)oA = make_float4(acc[mt][0]*dA.x, acc[mt][1]*dA.y,
                                       acc[mt][2]*dA.z, acc[mt][3]*dA.w);
            float* oB = &out[(size_t)bbB*T_LEN*NI + (size_t)t*NI + jjB];
            float4 dB = *(const float4*)oB;
            *(float4*)oB = make_float4(acc[mt][4]*dB.x, acc[mt][5]*dB.y,
                                       acc[mt][6]*dB.z, acc[mt][7]*dB.w);
        }
    }
}

extern "C" void kernel_launch(void* const* d_in, const int* in_sizes, int n_in,
                              void* d_out, int out_size, void* d_ws, size_t ws_size,
                              hipStream_t stream) {
    const float* x      = (const float*)d_in[0];
    const float* b_all  = (const float*)d_in[1];
    const float* a_all  = (const float*)d_in[2];
    const float* zi_all = (const float*)d_in[3];
    const float* W1     = (const float*)d_in[4];
    const float* b1     = (const float*)d_in[5];
    const float* w2     = (const float*)d_in[6];
    const int*   fidx   = (const int*)d_in[7];
    float* out = (float*)d_out;

    float* Pt  = (float*)d_ws;                      // [3000][6336] k-major (76.0MB)
    float* Vt  = Pt + (size_t)T_LEN * SEQ;          // [256][6400] (6.55MB)
    float* W1T = Vt + (size_t)NH * VTS;             // [256][3072] (3.15MB) => 85.7MB

    // filtfilt scratch lives in d_out (consumed before k_ugemm reuses it)
    double* Hd  = (double*)d_out;                   // [97][202][4]
    double* Mfd = Hd + (size_t)NF*LF*4;             // [97][16]
    double* Zef = Mfd + NF*16;                      // [97][15][64][4]
    double* Zeb = Zef + (size_t)NF*NSEG*64*4;
    double* Zfd = Zeb + (size_t)NF*NSEG*64*4;
    double* Zbd = Zfd + (size_t)NF*NSEG*64*4;
    float*  YRb = (float*)(Zbd + (size_t)NF*NSEG*64*4);   // [97][15][64]
    float*  Up  = out;                              // split-K partials (65.5 MB)

    hipLaunchKernelGGL(k_init, dim3(246), dim3(256), 0, stream,
                       x, W1, a_all, Pt, W1T, Hd, Mfd);
    hipLaunchKernelGGL(k_seg_fwd, dim3(NF, NSEG), dim3(64), 0, stream,
                       Pt, b_all, a_all, zi_all, YRb, Zef);
    hipLaunchKernelGGL(k_stitch, dim3(NF), dim3(64), 0, stream,
                       Zef, Mfd, Zfd);
    hipLaunchKernelGGL(k_seg_bwd, dim3(NF, NSEG), dim3(64), 0, stream,
                       Pt, b_all, a_all, zi_all, YRb, Hd, Zfd, Zeb);
    hipLaunchKernelGGL(k_stitch, dim3(NF), dim3(64), 0, stream,
                       Zeb, Mfd, Zbd);
    hipLaunchKernelGGL(k_corr_bwd, dim3(NF, 14), dim3(64), 0, stream,
                       Pt, Hd, Zbd);
    hipLaunchKernelGGL(k_ugemm, dim3(50, 2, KS), dim3(256), 0, stream,
                       Pt, W1, Up);
    hipLaunchKernelGGL(k_uvred, dim3(UPROWS/32), dim3(256), 0, stream,
                       Up, b1, w2, fidx, Vt);
    hipLaunchKernelGGL(k_delta, dim3(T_LEN), dim3(256), 0, stream,
                       Pt, fidx, out);
    hipLaunchKernelGGL(k_out, dim3((T_LEN+127)/128, (NB*NI)/128), dim3(256), 0, stream,
                       W1T, Vt, out);
}